// Round 2
// baseline (148.801 us; speedup 1.0000x reference)
//
#include <hip/hip_runtime.h>
#include <hip/hip_bf16.h>
#include <stdint.h>

#define BATCH 16384
#define MAXA 32
#define FEAT 768
#define HIDDEN 1024

__device__ __forceinline__ float bflo(uint32_t u){ return __uint_as_float(u << 16); }
__device__ __forceinline__ float bfhi(uint32_t u){ return __uint_as_float(u & 0xffff0000u); }

__device__ __forceinline__ void unpack8(uint4 u, float* d){
  d[0]=bflo(u.x); d[1]=bfhi(u.x);
  d[2]=bflo(u.y); d[3]=bfhi(u.y);
  d[4]=bflo(u.z); d[5]=bfhi(u.z);
  d[6]=bflo(u.w); d[7]=bfhi(u.w);
}

// fp32 -> bf16 round-to-nearest-even (inputs contain no NaN)
__device__ __forceinline__ uint16_t f2bf(float f){
  uint32_t u = __float_as_uint(f);
  return (uint16_t)((u + 0x7fffu + ((u >> 16) & 1u)) >> 16);
}

// ft_w is (HIDDEN, FEAT) row-major fp32; build wT (FEAT, HIDDEN) bf16 so a
// feature's 1024-wide column is contiguous (2 KB) -> coalesced uint4 gathers
// and half the L2 traffic of fp32.
__global__ __launch_bounds__(256) void transpose_ft(const float* __restrict__ w,
                                                    uint16_t* __restrict__ wT){
  int tid = blockIdx.x * 256 + threadIdx.x;
  int f = tid >> 10;        // / HIDDEN
  int h = tid & (HIDDEN-1); // % HIDDEN
  wT[tid] = f2bf(w[h * FEAT + f]);
}

// One wave per batch row. Lanes 0..31 own stm indices, 32..63 own nstm.
// Lane L accumulates hidden elems h = L*8+k and 512+L*8+k (k=0..7).
__global__ __launch_bounds__(256) void nn_fwd(
    const int* __restrict__ stm, const int* __restrict__ nstm,
    const uint16_t* __restrict__ wT, const float* __restrict__ bias,
    const float* __restrict__ outw, const float* __restrict__ outb,
    float* __restrict__ out)
{
  const int lane = threadIdx.x & 63;
  const int row  = blockIdx.x * 4 + (threadIdx.x >> 6);
  const int half = lane >> 5;   // 0 = stm, 1 = nstm
  const int pos  = lane & 31;

  const int* __restrict__ src = half ? nstm : stm;
  int idx = src[row * MAXA + pos];
  bool valid = idx >= 0;        // -1 padding -> no contribution
  // dedupe within each half: reference .at[].max() counts duplicates once
#pragma unroll
  for (int j = 0; j < 31; ++j) {
    int other = __shfl(idx, (half << 5) | j, 64);
    if (j < pos && other == idx) valid = false;
  }
  uint64_t mask = __ballot(valid);   // wave-uniform

  float accs[16], accn[16];
#pragma unroll
  for (int k = 0; k < 16; ++k) { accs[k] = 0.f; accn[k] = 0.f; }

  // stm features (mask bits 0..31)
  for (int j = 0; j < 32; ++j) {
    if (!((mask >> j) & 1ull)) continue;        // wave-uniform branch
    int f = __builtin_amdgcn_readlane(idx, j);  // uniform feature id
    const uint4* pw = (const uint4*)(wT + (size_t)f * HIDDEN);
    uint4 w0 = pw[lane];       // h = lane*8 .. +7
    uint4 w1 = pw[64 + lane];  // h = 512 + lane*8 .. +7
    float t[8];
    unpack8(w0, t);
#pragma unroll
    for (int k = 0; k < 8; ++k) accs[k] += t[k];
    unpack8(w1, t);
#pragma unroll
    for (int k = 0; k < 8; ++k) accs[8+k] += t[k];
  }
  // nstm features (mask bits 32..63)
  for (int j = 32; j < 64; ++j) {
    if (!((mask >> j) & 1ull)) continue;
    int f = __builtin_amdgcn_readlane(idx, j);
    const uint4* pw = (const uint4*)(wT + (size_t)f * HIDDEN);
    uint4 w0 = pw[lane];
    uint4 w1 = pw[64 + lane];
    float t[8];
    unpack8(w0, t);
#pragma unroll
    for (int k = 0; k < 8; ++k) accn[k] += t[k];
    unpack8(w1, t);
#pragma unroll
    for (int k = 0; k < 8; ++k) accn[8+k] += t[k];
  }

  // Epilogue: bias + clip01, fused 2048-dot with out_w, sigmoid. All fp32.
  const float4* b4 = (const float4*)bias;   // 256 float4
  const float4* o4 = (const float4*)outw;   // 512 float4
  float bb[16], ows[16], own[16];
  {
    float4 v;
    v = b4[2*lane];       bb[0]=v.x; bb[1]=v.y; bb[2]=v.z; bb[3]=v.w;
    v = b4[2*lane+1];     bb[4]=v.x; bb[5]=v.y; bb[6]=v.z; bb[7]=v.w;
    v = b4[128+2*lane];   bb[8]=v.x; bb[9]=v.y; bb[10]=v.z; bb[11]=v.w;
    v = b4[128+2*lane+1]; bb[12]=v.x; bb[13]=v.y; bb[14]=v.z; bb[15]=v.w;

    v = o4[2*lane];       ows[0]=v.x; ows[1]=v.y; ows[2]=v.z; ows[3]=v.w;
    v = o4[2*lane+1];     ows[4]=v.x; ows[5]=v.y; ows[6]=v.z; ows[7]=v.w;
    v = o4[128+2*lane];   ows[8]=v.x; ows[9]=v.y; ows[10]=v.z; ows[11]=v.w;
    v = o4[128+2*lane+1]; ows[12]=v.x; ows[13]=v.y; ows[14]=v.z; ows[15]=v.w;

    v = o4[256+2*lane];   own[0]=v.x; own[1]=v.y; own[2]=v.z; own[3]=v.w;
    v = o4[256+2*lane+1]; own[4]=v.x; own[5]=v.y; own[6]=v.z; own[7]=v.w;
    v = o4[384+2*lane];   own[8]=v.x; own[9]=v.y; own[10]=v.z; own[11]=v.w;
    v = o4[384+2*lane+1]; own[12]=v.x; own[13]=v.y; own[14]=v.z; own[15]=v.w;
  }
  float partial = 0.f;
#pragma unroll
  for (int k = 0; k < 16; ++k) {
    float hs = fminf(fmaxf(accs[k] + bb[k], 0.f), 1.f);
    float hn = fminf(fmaxf(accn[k] + bb[k], 0.f), 1.f);
    partial += hs * ows[k] + hn * own[k];
  }
#pragma unroll
  for (int off = 32; off > 0; off >>= 1)
    partial += __shfl_down(partial, off, 64);
  if (lane == 0) {
    float y = partial + outb[0];
    out[row] = 1.f / (1.f + __expf(-y));
  }
}

extern "C" void kernel_launch(void* const* d_in, const int* in_sizes, int n_in,
                              void* d_out, int out_size, void* d_ws, size_t ws_size,
                              hipStream_t stream) {
  const int*   stm  = (const int*)d_in[0];
  const int*   nstm = (const int*)d_in[1];
  const float* ftw  = (const float*)d_in[2];   // (1024, 768) fp32
  const float* ftb  = (const float*)d_in[3];   // (1024,) fp32
  const float* outw = (const float*)d_in[4];   // (2048,) fp32
  const float* outb = (const float*)d_in[5];   // (1,) fp32
  uint16_t* wT = (uint16_t*)d_ws;              // 768*1024*2 B = 1.5 MB

  transpose_ft<<<(FEAT * HIDDEN) / 256, 256, 0, stream>>>(ftw, wT);
  nn_fwd<<<BATCH / 4, 256, 0, stream>>>(stm, nstm, wT, ftb, outw, outb,
                                        (float*)d_out);
}

// Round 3
// 124.258 us; speedup vs baseline: 1.1975x; 1.1975x over previous
//
#include <hip/hip_runtime.h>
#include <hip/hip_bf16.h>
#include <stdint.h>

#define BATCH 16384
#define MAXA 32
#define FEAT 768
#define HIDDEN 1024

// ---------------------------------------------------------------------------
// Prep: per-hidden-column int8 quantization of ft_w.
// ft_w is (HIDDEN, FEAT) row-major fp32; w[f][h] = ftw[h*FEAT + f].
// Block h (768 threads): col max -> s_h = max/127, q = rnd(w/s_h) + 128 (u8),
// stored transposed: wQ[f*HIDDEN + h] so a feature's 1024 h are 1 KB contiguous.
// ---------------------------------------------------------------------------
__global__ __launch_bounds__(768) void quantize_ft(const float* __restrict__ ftw,
                                                   uint8_t* __restrict__ wQ,
                                                   float* __restrict__ scale) {
  const int h = blockIdx.x;
  const int f = threadIdx.x;
  const float w = ftw[h * FEAT + f];
  float a = fabsf(w);
#pragma unroll
  for (int off = 32; off > 0; off >>= 1)
    a = fmaxf(a, __shfl_xor(a, off, 64));
  __shared__ float red[12];
  __shared__ float inv_sh;
  if ((threadIdx.x & 63) == 0) red[threadIdx.x >> 6] = a;
  __syncthreads();
  if (threadIdx.x == 0) {
    float m = red[0];
#pragma unroll
    for (int i = 1; i < 12; ++i) m = fmaxf(m, red[i]);
    m = fmaxf(m, 1e-20f);
    scale[h] = m / 127.f;
    inv_sh = 127.f / m;
  }
  __syncthreads();
  int q = __float2int_rn(w * inv_sh);          // [-127, 127]
  wQ[(size_t)f * HIDDEN + h] = (uint8_t)(q + 128);
}

// unpack a u32 (4 u8, h-consecutive) into two u16-pairs and accumulate.
// acc[2k]   holds (h+0 lo16, h+1 hi16); acc[2k+1] holds (h+2, h+3).
// Plain u32 add == packed u16 add: field max = 32*255 = 8160, never carries.
__device__ __forceinline__ void acc16(uint32_t* acc, uint4 w) {
  acc[0] += __builtin_amdgcn_perm(0u, w.x, 0x0c010c00u);
  acc[1] += __builtin_amdgcn_perm(0u, w.x, 0x0c030c02u);
  acc[2] += __builtin_amdgcn_perm(0u, w.y, 0x0c010c00u);
  acc[3] += __builtin_amdgcn_perm(0u, w.y, 0x0c030c02u);
  acc[4] += __builtin_amdgcn_perm(0u, w.z, 0x0c010c00u);
  acc[5] += __builtin_amdgcn_perm(0u, w.z, 0x0c030c02u);
  acc[6] += __builtin_amdgcn_perm(0u, w.w, 0x0c010c00u);
  acc[7] += __builtin_amdgcn_perm(0u, w.w, 0x0c030c02u);
}

// One wave per batch row. Lane L owns h = L*16 .. L*16+15 for BOTH sides.
// Lanes 0..31 carry stm indices, 32..63 carry nstm indices (for dedupe/ballot).
__global__ __launch_bounds__(256) void nn_fwd(
    const int* __restrict__ stm, const int* __restrict__ nstm,
    const uint8_t* __restrict__ wQ, const float* __restrict__ scale,
    const float* __restrict__ bias, const float* __restrict__ outw,
    const float* __restrict__ outb, float* __restrict__ out)
{
  const int lane = threadIdx.x & 63;
  const int row  = blockIdx.x * 4 + (threadIdx.x >> 6);
  const int half = lane >> 5;       // 0 = stm, 1 = nstm
  const int pos  = lane & 31;

  const int* __restrict__ src = half ? nstm : stm;
  int idx = src[row * MAXA + pos];
  bool valid = idx >= 0;            // -1 padding -> no contribution
  // dedupe within each half: reference .at[].max() counts duplicates once
#pragma unroll
  for (int j = 0; j < 31; ++j) {
    int other = __shfl(idx, (half << 5) | j, 64);
    if (j < pos && other == idx) valid = false;
  }
  const uint64_t mask = __ballot(valid);      // wave-uniform

  uint32_t accs[8], accn[8];
#pragma unroll
  for (int k = 0; k < 8; ++k) { accs[k] = 0u; accn[k] = 0u; }

  const uint8_t* wbase = wQ + (size_t)lane * 16;

  // stm features: walk set bits pairwise so two 1 KB column loads are in flight
  {
    uint32_t ms = (uint32_t)(mask & 0xffffffffull);
    while (ms) {
      int j0 = __builtin_ctz(ms); ms &= ms - 1;
      int f0 = __builtin_amdgcn_readlane(idx, j0);
      const uint4* p0 = (const uint4*)(wbase + (size_t)f0 * HIDDEN);
      if (ms) {
        int j1 = __builtin_ctz(ms); ms &= ms - 1;
        int f1 = __builtin_amdgcn_readlane(idx, j1);
        const uint4* p1 = (const uint4*)(wbase + (size_t)f1 * HIDDEN);
        uint4 w0 = *p0;
        uint4 w1 = *p1;
        acc16(accs, w0);
        acc16(accs, w1);
      } else {
        acc16(accs, *p0);
      }
    }
  }
  // nstm features
  {
    uint32_t ms = (uint32_t)(mask >> 32);
    while (ms) {
      int j0 = __builtin_ctz(ms); ms &= ms - 1;
      int f0 = __builtin_amdgcn_readlane(idx, 32 + j0);
      const uint4* p0 = (const uint4*)(wbase + (size_t)f0 * HIDDEN);
      if (ms) {
        int j1 = __builtin_ctz(ms); ms &= ms - 1;
        int f1 = __builtin_amdgcn_readlane(idx, 32 + j1);
        const uint4* p1 = (const uint4*)(wbase + (size_t)f1 * HIDDEN);
        uint4 w0 = *p0;
        uint4 w1 = *p1;
        acc16(accn, w0);
        acc16(accn, w1);
      } else {
        acc16(accn, *p0);
      }
    }
  }

  const int bs = 128 * __builtin_popcountll(mask & 0xffffffffull);
  const int bn = 128 * __builtin_popcountll(mask >> 32);

  // Epilogue: dequant + bias + clip01, fused 2048-dot with out_w, sigmoid.
  const int hbase = lane * 16;
  float sc[16], bb[16], ows[16], own[16];
  {
    const float4* s4 = (const float4*)(scale + hbase);
    const float4* b4 = (const float4*)(bias + hbase);
    const float4* oS = (const float4*)(outw + hbase);
    const float4* oN = (const float4*)(outw + HIDDEN + hbase);
#pragma unroll
    for (int q = 0; q < 4; ++q) {
      float4 v;
      v = s4[q]; sc[4*q]=v.x; sc[4*q+1]=v.y; sc[4*q+2]=v.z; sc[4*q+3]=v.w;
      v = b4[q]; bb[4*q]=v.x; bb[4*q+1]=v.y; bb[4*q+2]=v.z; bb[4*q+3]=v.w;
      v = oS[q]; ows[4*q]=v.x; ows[4*q+1]=v.y; ows[4*q+2]=v.z; ows[4*q+3]=v.w;
      v = oN[q]; own[4*q]=v.x; own[4*q+1]=v.y; own[4*q+2]=v.z; own[4*q+3]=v.w;
    }
  }
  float partial = 0.f;
#pragma unroll
  for (int k = 0; k < 16; ++k) {
    uint32_t as = accs[k >> 1], an = accn[k >> 1];
    int qs = (int)((k & 1) ? (as >> 16) : (as & 0xffffu)) - bs;
    int qn = (int)((k & 1) ? (an >> 16) : (an & 0xffffu)) - bn;
    float hs = fminf(fmaxf(fmaf((float)qs, sc[k], bb[k]), 0.f), 1.f);
    float hn = fminf(fmaxf(fmaf((float)qn, sc[k], bb[k]), 0.f), 1.f);
    partial += hs * ows[k] + hn * own[k];
  }
#pragma unroll
  for (int off = 32; off > 0; off >>= 1)
    partial += __shfl_down(partial, off, 64);
  if (lane == 0) {
    float y = partial + outb[0];
    out[row] = 1.f / (1.f + __expf(-y));
  }
}

extern "C" void kernel_launch(void* const* d_in, const int* in_sizes, int n_in,
                              void* d_out, int out_size, void* d_ws, size_t ws_size,
                              hipStream_t stream) {
  const int*   stm  = (const int*)d_in[0];
  const int*   nstm = (const int*)d_in[1];
  const float* ftw  = (const float*)d_in[2];   // (1024, 768) fp32
  const float* ftb  = (const float*)d_in[3];   // (1024,) fp32
  const float* outw = (const float*)d_in[4];   // (2048,) fp32
  const float* outb = (const float*)d_in[5];   // (1,) fp32

  uint8_t* wQ    = (uint8_t*)d_ws;                      // 768 KB
  float*   scale = (float*)((uint8_t*)d_ws + (size_t)FEAT * HIDDEN);  // 4 KB

  quantize_ft<<<HIDDEN, FEAT, 0, stream>>>(ftw, wQ, scale);
  nn_fwd<<<BATCH / 4, 256, 0, stream>>>(stm, nstm, wQ, scale, ftb, outw, outb,
                                        (float*)d_out);
}

// Round 4
// 120.100 us; speedup vs baseline: 1.2390x; 1.0346x over previous
//
#include <hip/hip_runtime.h>
#include <hip/hip_bf16.h>
#include <stdint.h>

#define BATCH 16384
#define MAXA 32
#define FEAT 768
#define HIDDEN 1024

// ---------------------------------------------------------------------------
// Prep 1: per-hidden-column max -> scale/invscale; also init the dummy zero
// column wQ[768][*] = 128 (q=0 biased). Blocks 0..1023 = h; block 1024 = dummy.
// ---------------------------------------------------------------------------
__global__ __launch_bounds__(256) void scale_k(const float* __restrict__ ftw,
                                               float* __restrict__ scale,
                                               float* __restrict__ invsc,
                                               uint8_t* __restrict__ wQ) {
  if (blockIdx.x == HIDDEN) {
    if (threadIdx.x < 64) {
      uint4 v; v.x = v.y = v.z = v.w = 0x80808080u;
      ((uint4*)(wQ + (size_t)FEAT * HIDDEN))[threadIdx.x] = v;
    }
    return;
  }
  const int h = blockIdx.x;
  float a = 0.f;
#pragma unroll
  for (int p = 0; p < 3; ++p)
    a = fmaxf(a, fabsf(ftw[h * FEAT + p * 256 + threadIdx.x]));
#pragma unroll
  for (int off = 32; off > 0; off >>= 1)
    a = fmaxf(a, __shfl_xor(a, off, 64));
  __shared__ float red[4];
  if ((threadIdx.x & 63) == 0) red[threadIdx.x >> 6] = a;
  __syncthreads();
  if (threadIdx.x == 0) {
    float m = fmaxf(fmaxf(red[0], red[1]), fmaxf(red[2], red[3]));
    m = fmaxf(m, 1e-20f);
    scale[h] = m / 127.f;
    invsc[h] = 127.f / m;
  }
}

// ---------------------------------------------------------------------------
// Prep 2: quantize + transpose, LDS-tiled (64 f x 64 h), coalesced fp32 reads
// and coalesced 16 B stores (vs the old 786k-byte scatter).
// ---------------------------------------------------------------------------
__global__ __launch_bounds__(256) void tilequant(const float* __restrict__ ftw,
                                                 const float* __restrict__ invsc,
                                                 uint8_t* __restrict__ wQ) {
  const int f0 = (blockIdx.x % (FEAT / 64)) * 64;
  const int h0 = (blockIdx.x / (FEAT / 64)) * 64;
  __shared__ uint8_t tile[64][80];   // stride 80: 16B-aligned rows
  __shared__ float inv[64];
  if (threadIdx.x < 64) inv[threadIdx.x] = invsc[h0 + threadIdx.x];
  __syncthreads();
  const int ff = threadIdx.x & 63;
  const int hb = threadIdx.x >> 6;
#pragma unroll
  for (int p = 0; p < 16; ++p) {
    int hh = p * 4 + hb;
    float w = ftw[(size_t)(h0 + hh) * FEAT + f0 + ff];
    int q = __float2int_rn(w * inv[hh]);      // [-127,127]
    tile[ff][hh] = (uint8_t)(q + 128);
  }
  __syncthreads();
  const int fs = threadIdx.x >> 2, part = threadIdx.x & 3;  // 64 f x 4 parts
  uint4 v = *(const uint4*)&tile[fs][part * 16];
  *(uint4*)(wQ + (size_t)(f0 + fs) * HIDDEN + h0 + part * 16) = v;
}

// unpack a u32 (4 u8, h-consecutive) into two u16-pairs and accumulate.
// Plain u32 add == packed u16 add: field max = 32*255 = 8160, never carries.
__device__ __forceinline__ void acc16(uint32_t* acc, uint4 w) {
  acc[0] += __builtin_amdgcn_perm(0u, w.x, 0x0c010c00u);
  acc[1] += __builtin_amdgcn_perm(0u, w.x, 0x0c030c02u);
  acc[2] += __builtin_amdgcn_perm(0u, w.y, 0x0c010c00u);
  acc[3] += __builtin_amdgcn_perm(0u, w.y, 0x0c030c02u);
  acc[4] += __builtin_amdgcn_perm(0u, w.z, 0x0c010c00u);
  acc[5] += __builtin_amdgcn_perm(0u, w.z, 0x0c030c02u);
  acc[6] += __builtin_amdgcn_perm(0u, w.w, 0x0c010c00u);
  acc[7] += __builtin_amdgcn_perm(0u, w.w, 0x0c030c02u);
}

// One wave per batch row. Lane L owns h = L*16 .. +15 for BOTH sides.
// Branch-free gather: invalid/duplicate features -> dummy zero column f=768,
// so the loop is a fixed 32x2 loads with wave-uniform (scalar) column bases.
__global__ __launch_bounds__(256) void nn_fwd(
    const int* __restrict__ stm, const int* __restrict__ nstm,
    const uint8_t* __restrict__ wQ, const float* __restrict__ scale,
    const float* __restrict__ bias, const float* __restrict__ outw,
    const float* __restrict__ outb, float* __restrict__ out)
{
  const int lane = threadIdx.x & 63;
  const int row  = blockIdx.x * 4 + (threadIdx.x >> 6);
  const int half = lane >> 5;       // 0 = stm, 1 = nstm
  const int pos  = lane & 31;

  const int* __restrict__ src = half ? nstm : stm;
  int idx = src[row * MAXA + pos];
  bool valid = idx >= 0;            // -1 padding -> no contribution
  // dedupe within each half: reference .at[].max() counts duplicates once
#pragma unroll
  for (int j = 0; j < 31; ++j) {
    int other = __shfl(idx, (half << 5) | j, 64);
    if (j < pos && other == idx) valid = false;
  }
  const int fmap = valid ? idx : FEAT;   // dummy zero column

  uint32_t accs[8], accn[8];
#pragma unroll
  for (int k = 0; k < 8; ++k) { accs[k] = 0u; accn[k] = 0u; }

  // 32 iterations x 2 sides, fully unrolled; column base is wave-uniform ->
  // global_load_dwordx4 saddr form, VALU ~= acc16 only.
#pragma unroll
  for (int j = 0; j < 32; ++j) {
    int fs_ = __builtin_amdgcn_readlane(fmap, j);
    int fn_ = __builtin_amdgcn_readlane(fmap, 32 + j);
    const uint4* ps = (const uint4*)(wQ + (size_t)fs_ * HIDDEN);
    const uint4* pn = (const uint4*)(wQ + (size_t)fn_ * HIDDEN);
    uint4 ws_ = ps[lane];
    uint4 wn_ = pn[lane];
    acc16(accs, ws_);
    acc16(accn, wn_);
  }

  // Every position contributes +128 per element: de-bias is constant 32*128.
  const int DB = 32 * 128;

  // Epilogue: dequant + bias + clip01, fused 2048-dot with out_w, sigmoid.
  const int hbase = lane * 16;
  float sc[16], bb[16], ows[16], own[16];
  {
    const float4* s4 = (const float4*)(scale + hbase);
    const float4* b4 = (const float4*)(bias + hbase);
    const float4* oS = (const float4*)(outw + hbase);
    const float4* oN = (const float4*)(outw + HIDDEN + hbase);
#pragma unroll
    for (int q = 0; q < 4; ++q) {
      float4 v;
      v = s4[q]; sc[4*q]=v.x; sc[4*q+1]=v.y; sc[4*q+2]=v.z; sc[4*q+3]=v.w;
      v = b4[q]; bb[4*q]=v.x; bb[4*q+1]=v.y; bb[4*q+2]=v.z; bb[4*q+3]=v.w;
      v = oS[q]; ows[4*q]=v.x; ows[4*q+1]=v.y; ows[4*q+2]=v.z; ows[4*q+3]=v.w;
      v = oN[q]; own[4*q]=v.x; own[4*q+1]=v.y; own[4*q+2]=v.z; own[4*q+3]=v.w;
    }
  }
  float partial = 0.f;
#pragma unroll
  for (int k = 0; k < 16; ++k) {
    uint32_t as = accs[k >> 1], an = accn[k >> 1];
    int qs = (int)((k & 1) ? (as >> 16) : (as & 0xffffu)) - DB;
    int qn = (int)((k & 1) ? (an >> 16) : (an & 0xffffu)) - DB;
    float hs = fminf(fmaxf(fmaf((float)qs, sc[k], bb[k]), 0.f), 1.f);
    float hn = fminf(fmaxf(fmaf((float)qn, sc[k], bb[k]), 0.f), 1.f);
    partial += hs * ows[k] + hn * own[k];
  }
#pragma unroll
  for (int off = 32; off > 0; off >>= 1)
    partial += __shfl_down(partial, off, 64);
  if (lane == 0) {
    float y = partial + outb[0];
    out[row] = 1.f / (1.f + __expf(-y));
  }
}

extern "C" void kernel_launch(void* const* d_in, const int* in_sizes, int n_in,
                              void* d_out, int out_size, void* d_ws, size_t ws_size,
                              hipStream_t stream) {
  const int*   stm  = (const int*)d_in[0];
  const int*   nstm = (const int*)d_in[1];
  const float* ftw  = (const float*)d_in[2];   // (1024, 768) fp32
  const float* ftb  = (const float*)d_in[3];   // (1024,) fp32
  const float* outw = (const float*)d_in[4];   // (2048,) fp32
  const float* outb = (const float*)d_in[5];   // (1,) fp32

  uint8_t* wQ    = (uint8_t*)d_ws;                         // (768+1)*1024 B
  float*   scale = (float*)(wQ + (size_t)(FEAT + 1) * HIDDEN);   // 4 KB
  float*   invsc = scale + HIDDEN;                               // 4 KB

  scale_k<<<HIDDEN + 1, 256, 0, stream>>>(ftw, scale, invsc, wQ);
  tilequant<<<(FEAT / 64) * (HIDDEN / 64), 256, 0, stream>>>(ftw, invsc, wQ);
  nn_fwd<<<BATCH / 4, 256, 0, stream>>>(stm, nstm, wQ, scale, ftb, outw, outb,
                                        (float*)d_out);
}